// Round 1
// baseline (958.600 us; speedup 1.0000x reference)
//
#include <hip/hip_runtime.h>

// Problem: B=2, H=16, S=2048, D=64, fp32, temperature=8, int mask (0 = masked).
// Outputs concatenated: output [B,H,S,D] (4.19M f32) then attn [B,H,S,S] (134M f32).

#define S 2048
#define D 64
#define HH 16
#define BB 2
#define LDK 72  // LDS row stride in bf16 elems (64 + 8 pad -> 144B, 2-way bank alias = free)

typedef __attribute__((ext_vector_type(8))) short short8;
typedef __attribute__((ext_vector_type(8))) unsigned short ushort8;
typedef __attribute__((ext_vector_type(4))) float f32x4;

__device__ __forceinline__ unsigned short f2bf(float f) {
  unsigned int u = __builtin_bit_cast(unsigned int, f);
  u += 0x7fffu + ((u >> 16) & 1u);  // RNE
  return (unsigned short)(u >> 16);
}

__device__ __forceinline__ ushort8 cvt8(float4 a, float4 b) {
  ushort8 r;
  r[0] = f2bf(a.x); r[1] = f2bf(a.y); r[2] = f2bf(a.z); r[3] = f2bf(a.w);
  r[4] = f2bf(b.x); r[5] = f2bf(b.y); r[6] = f2bf(b.z); r[7] = f2bf(b.w);
  return r;
}

// Block = 256 threads (4 waves). Each block: one (b,h), 64 q-rows.
// Wave w owns q-rows [w*16, w*16+16). MFMA 16x16x32 bf16.
// A-frag:  A[m=lane&15][k=quad*8+j]   (m120-verified)
// B-frag:  B[k=quad*8+j][n=lane&15]
// C/D:     row=quad*4+reg, col=lane&15 (m89/m91-verified)
__global__ __launch_bounds__(256) void attn_kernel(
    const float* __restrict__ Qg, const float* __restrict__ Kg,
    const float* __restrict__ Vg, const int* __restrict__ Mg,
    float* __restrict__ Og, float* __restrict__ Ag) {
  __shared__ unsigned short Kt[64 * LDK];  // K tile, row-major [key][d]
  __shared__ unsigned short Vt[64 * LDK];  // V tile, TRANSPOSED [d][key]
  __shared__ unsigned short Qs[64 * LDK];  // Q tile; reused as P tile in pass 2

  const int tid = threadIdx.x;
  const int w = tid >> 6;
  const int lane = tid & 63;
  const int ln15 = lane & 15;
  const int quad = lane >> 4;

  const int qtile = blockIdx.x;  // 0..31
  const int bh = blockIdx.y;     // 0..31  (= b*H + h)
  const int b = bh >> 4;

  const size_t qkvbase = (size_t)bh * S * D;
  const int q0 = qtile * 64;

  // ---- stage Q tile (each wave writes & reads its own 16 rows) ----
  {
    const int trow = tid >> 2;
    const int tcol = (tid & 3) << 4;
    const float4* src =
        reinterpret_cast<const float4*>(Qg + qkvbase + (size_t)(q0 + trow) * D + tcol);
    float4 x0 = src[0], x1 = src[1], x2 = src[2], x3 = src[3];
    *reinterpret_cast<ushort8*>(&Qs[trow * LDK + tcol]) = cvt8(x0, x1);
    *reinterpret_cast<ushort8*>(&Qs[trow * LDK + tcol + 8]) = cvt8(x2, x3);
  }
  __syncthreads();
  const short8 aq0 = *reinterpret_cast<const short8*>(&Qs[(w * 16 + ln15) * LDK + (quad << 3)]);
  const short8 aq1 = *reinterpret_cast<const short8*>(&Qs[(w * 16 + ln15) * LDK + 32 + (quad << 3)]);

  const int qbase = q0 + w * 16 + quad * 4;  // first of this lane's 4 C-rows
  const int* maskrow[4];
#pragma unroll
  for (int r = 0; r < 4; r++)
    maskrow[r] = Mg + (size_t)b * S * S + (size_t)(qbase + r) * S;

  // =============== PASS 1: row sums of exp(masked scores) ===============
  float lsum[4] = {0.f, 0.f, 0.f, 0.f};
  for (int k0 = 0; k0 < S; k0 += 64) {
    __syncthreads();
    {
      const int trow = tid >> 2;
      const int tcol = (tid & 3) << 4;
      const float4* src =
          reinterpret_cast<const float4*>(Kg + qkvbase + (size_t)(k0 + trow) * D + tcol);
      float4 x0 = src[0], x1 = src[1], x2 = src[2], x3 = src[3];
      *reinterpret_cast<ushort8*>(&Kt[trow * LDK + tcol]) = cvt8(x0, x1);
      *reinterpret_cast<ushort8*>(&Kt[trow * LDK + tcol + 8]) = cvt8(x2, x3);
    }
    __syncthreads();
#pragma unroll
    for (int kt = 0; kt < 4; kt++) {
      f32x4 acc = {0.f, 0.f, 0.f, 0.f};
      short8 bk0 = *reinterpret_cast<const short8*>(&Kt[(kt * 16 + ln15) * LDK + (quad << 3)]);
      short8 bk1 = *reinterpret_cast<const short8*>(&Kt[(kt * 16 + ln15) * LDK + 32 + (quad << 3)]);
      acc = __builtin_amdgcn_mfma_f32_16x16x32_bf16(aq0, bk0, acc, 0, 0, 0);
      acc = __builtin_amdgcn_mfma_f32_16x16x32_bf16(aq1, bk1, acc, 0, 0, 0);
      const int key = k0 + kt * 16 + ln15;
#pragma unroll
      for (int r = 0; r < 4; r++) {
        int mv = maskrow[r][key];
        float e = __expf(acc[r] * 0.125f);
        lsum[r] += mv ? e : 0.f;
      }
    }
  }
#pragma unroll
  for (int r = 0; r < 4; r++) {
    float v = lsum[r];
    v += __shfl_xor(v, 1, 64);
    v += __shfl_xor(v, 2, 64);
    v += __shfl_xor(v, 4, 64);
    v += __shfl_xor(v, 8, 64);
    lsum[r] = (v > 0.f) ? 1.f / v : 0.f;  // lsum now holds 1/l (0 if fully masked)
  }

  // =============== PASS 2: write attn, accumulate O = P @ V ===============
  float* attnrow[4];
#pragma unroll
  for (int r = 0; r < 4; r++)
    attnrow[r] = Ag + ((size_t)bh * S + (size_t)(qbase + r)) * S;

  f32x4 oacc[4] = {{0.f, 0.f, 0.f, 0.f}, {0.f, 0.f, 0.f, 0.f},
                   {0.f, 0.f, 0.f, 0.f}, {0.f, 0.f, 0.f, 0.f}};
  unsigned short* Ps = Qs;  // reuse (wave-local rows w*16..w*16+16)

  for (int k0 = 0; k0 < S; k0 += 64) {
    __syncthreads();
    {
      const int trow = tid >> 2;
      const int tcol = (tid & 3) << 4;
      const float4* src =
          reinterpret_cast<const float4*>(Kg + qkvbase + (size_t)(k0 + trow) * D + tcol);
      float4 x0 = src[0], x1 = src[1], x2 = src[2], x3 = src[3];
      *reinterpret_cast<ushort8*>(&Kt[trow * LDK + tcol]) = cvt8(x0, x1);
      *reinterpret_cast<ushort8*>(&Kt[trow * LDK + tcol + 8]) = cvt8(x2, x3);
      const float4* vsrc =
          reinterpret_cast<const float4*>(Vg + qkvbase + (size_t)(k0 + trow) * D + tcol);
      float4 y0 = vsrc[0], y1 = vsrc[1], y2 = vsrc[2], y3 = vsrc[3];
      float yy[16] = {y0.x, y0.y, y0.z, y0.w, y1.x, y1.y, y1.z, y1.w,
                      y2.x, y2.y, y2.z, y2.w, y3.x, y3.y, y3.z, y3.w};
#pragma unroll
      for (int j = 0; j < 16; j++) Vt[(tcol + j) * LDK + trow] = f2bf(yy[j]);
    }
    __syncthreads();
#pragma unroll
    for (int kt = 0; kt < 4; kt++) {
      f32x4 acc = {0.f, 0.f, 0.f, 0.f};
      short8 bk0 = *reinterpret_cast<const short8*>(&Kt[(kt * 16 + ln15) * LDK + (quad << 3)]);
      short8 bk1 = *reinterpret_cast<const short8*>(&Kt[(kt * 16 + ln15) * LDK + 32 + (quad << 3)]);
      acc = __builtin_amdgcn_mfma_f32_16x16x32_bf16(aq0, bk0, acc, 0, 0, 0);
      acc = __builtin_amdgcn_mfma_f32_16x16x32_bf16(aq1, bk1, acc, 0, 0, 0);
      const int key = k0 + kt * 16 + ln15;
#pragma unroll
      for (int r = 0; r < 4; r++) {
        int mv = maskrow[r][key];
        float e = __expf(acc[r] * 0.125f);
        e = mv ? e : 0.f;
        float p = e * lsum[r];
        attnrow[r][key] = p;
        Ps[(w * 16 + quad * 4 + r) * LDK + kt * 16 + ln15] = f2bf(p);
      }
    }
    // P (C-layout) was round-tripped through LDS -> read back in A-layout.
#pragma unroll
    for (int kc = 0; kc < 2; kc++) {
      short8 ap =
          *reinterpret_cast<const short8*>(&Ps[(w * 16 + ln15) * LDK + kc * 32 + (quad << 3)]);
#pragma unroll
      for (int c = 0; c < 4; c++) {
        short8 bv =
            *reinterpret_cast<const short8*>(&Vt[(c * 16 + ln15) * LDK + kc * 32 + (quad << 3)]);
        oacc[c] = __builtin_amdgcn_mfma_f32_16x16x32_bf16(ap, bv, oacc[c], 0, 0, 0);
      }
    }
  }

  // ---- epilogue: O store (C-layout: row=quad*4+r, col=c*16+ln15) ----
#pragma unroll
  for (int c = 0; c < 4; c++) {
#pragma unroll
    for (int r = 0; r < 4; r++) {
      Og[qkvbase + (size_t)(qbase + r) * D + c * 16 + ln15] = oacc[c][r];
    }
  }
}

extern "C" void kernel_launch(void* const* d_in, const int* in_sizes, int n_in,
                              void* d_out, int out_size, void* d_ws, size_t ws_size,
                              hipStream_t stream) {
  const float* q = (const float*)d_in[0];
  const float* k = (const float*)d_in[1];
  const float* v = (const float*)d_in[2];
  const int* m = (const int*)d_in[3];
  float* outp = (float*)d_out;
  float* attnp = outp + (size_t)BB * HH * S * D;  // attn follows output
  dim3 grid(S / 64, BB * HH);
  attn_kernel<<<grid, 256, 0, stream>>>(q, k, v, m, outp, attnp);
}

// Round 2
// 804.479 us; speedup vs baseline: 1.1916x; 1.1916x over previous
//
#include <hip/hip_runtime.h>

// B=2,H=16,S=2048,D=64 fp32; temp=8; outputs: O [B,H,S,D] then attn [B,H,S,S].
// Strategy: S^T = K·Q^T per MFMA tile so each lane owns 4 consecutive keys of one
// query -> float4 attn stores, 1 bitmask u64/lane/k-tile, scalar lsum.

#define S 2048
#define D 64
#define HH 16
#define BB 2
#define LDK 72      // bf16 elems per LDS row for K/V tiles (144B; 2-way alias free)
#define PSTR 36     // dwords per P-row (16 queries x 36 dw per wave)

typedef __attribute__((ext_vector_type(8))) short short8;
typedef __attribute__((ext_vector_type(4))) float f32x4;

__device__ __forceinline__ unsigned int f2bfu(float f) {
  unsigned int u = __builtin_bit_cast(unsigned int, f);
  u += 0x7fffu + ((u >> 16) & 1u);  // RNE
  return u >> 16;
}
__device__ __forceinline__ unsigned int packbf2(float a, float b) {
  return f2bfu(a) | (f2bfu(b) << 16);
}
__device__ __forceinline__ short8 cvt8(float4 a, float4 b) {
  union { unsigned int u[4]; short8 s; } r;
  r.u[0] = packbf2(a.x, a.y); r.u[1] = packbf2(a.z, a.w);
  r.u[2] = packbf2(b.x, b.y); r.u[3] = packbf2(b.z, b.w);
  return r.s;
}

// ---- pre-pass: pack mask ints -> 1 bit per element (u64 covers 64 keys) ----
__global__ __launch_bounds__(256) void pack_mask_kernel(
    const int* __restrict__ m, unsigned long long* __restrict__ bits) {
  int wid = blockIdx.x * 4 + (threadIdx.x >> 6);
  int lane = threadIdx.x & 63;
  int v = m[(size_t)wid * 64 + lane];
  unsigned long long b = __ballot(v != 0);
  if (lane == 0) bits[wid] = b;
}

__global__ __launch_bounds__(256) void attn_kernel(
    const float* __restrict__ Qg, const float* __restrict__ Kg,
    const float* __restrict__ Vg, const unsigned long long* __restrict__ Mb,
    float* __restrict__ Og, float* __restrict__ Ag) {
  __shared__ unsigned short Kt[64 * LDK];
  __shared__ unsigned short Vt[64 * LDK];
  __shared__ unsigned int Pp[4 * 16 * PSTR];  // per-wave P tile (bf16 pairs)

  const int tid = threadIdx.x;
  const int w = tid >> 6;
  const int lane = tid & 63;
  const int ln15 = lane & 15;
  const int quad = lane >> 4;

  const int bh = blockIdx.x;    // bh fastest -> each XCD sees ~4 heads (K/V L2-resident)
  const int qtile = blockIdx.y;
  const int b = bh >> 4;
  const size_t qkvbase = (size_t)bh * S * D;
  const int q0 = qtile * 64;
  const int qrow = q0 + w * 16 + ln15;  // this lane's query

  // Q fragments direct from global (no LDS): A/B-frag k = quad*8+j
  const float4* qp = reinterpret_cast<const float4*>(Qg + qkvbase + (size_t)qrow * D);
  short8 aq0, aq1;
  {
    float4 a0 = qp[quad * 2], a1 = qp[quad * 2 + 1];
    float4 b0 = qp[8 + quad * 2], b1 = qp[8 + quad * 2 + 1];
    aq0 = cvt8(a0, a1);
    aq1 = cvt8(b0, b1);
  }

  const unsigned long long* mrow = Mb + ((size_t)b * S + qrow) * (S / 64);

  const int trow = tid >> 2;          // staging: key row
  const int tcol = (tid & 3) << 4;    // staging: d offset (16 floats per thread)

  // =============== PASS 1: per-query sum of exp(masked scores) ===============
  float lsum = 0.f;
  float4 kf0, kf1, kf2, kf3;
  {
    const float4* src = reinterpret_cast<const float4*>(Kg + qkvbase + (size_t)trow * D + tcol);
    kf0 = src[0]; kf1 = src[1]; kf2 = src[2]; kf3 = src[3];
  }
  unsigned long long mw = mrow[0];
  for (int t = 0; t < 32; ++t) {
    __syncthreads();
    *reinterpret_cast<short8*>(&Kt[trow * LDK + tcol]) = cvt8(kf0, kf1);
    *reinterpret_cast<short8*>(&Kt[trow * LDK + tcol + 8]) = cvt8(kf2, kf3);
    __syncthreads();
    if (t < 31) {
      const float4* src = reinterpret_cast<const float4*>(
          Kg + qkvbase + (size_t)((t + 1) * 64 + trow) * D + tcol);
      kf0 = src[0]; kf1 = src[1]; kf2 = src[2]; kf3 = src[3];
    }
    unsigned long long mwn = (t < 31) ? mrow[t + 1] : 0ULL;
#pragma unroll
    for (int kt = 0; kt < 4; ++kt) {
      short8 bk0 = *reinterpret_cast<const short8*>(&Kt[(kt * 16 + ln15) * LDK + (quad << 3)]);
      short8 bk1 = *reinterpret_cast<const short8*>(&Kt[(kt * 16 + ln15) * LDK + 32 + (quad << 3)]);
      f32x4 acc = {0.f, 0.f, 0.f, 0.f};
      acc = __builtin_amdgcn_mfma_f32_16x16x32_bf16(bk0, aq0, acc, 0, 0, 0);
      acc = __builtin_amdgcn_mfma_f32_16x16x32_bf16(bk1, aq1, acc, 0, 0, 0);
      unsigned int nib = (unsigned int)(mw >> (kt * 16 + quad * 4)) & 0xFu;
#pragma unroll
      for (int r = 0; r < 4; ++r) {
        float e = __expf(acc[r] * 0.125f);
        lsum += ((nib >> r) & 1u) ? e : 0.f;
      }
    }
    mw = mwn;
  }
  lsum += __shfl_xor(lsum, 16, 64);
  lsum += __shfl_xor(lsum, 32, 64);
  const float rinv = (lsum > 0.f) ? 1.f / lsum : 0.f;

  // =============== PASS 2: write attn (float4), O = P·V ===============
  float* arow = Ag + ((size_t)bh * S + qrow) * S;
  f32x4 oacc[4] = {{0.f, 0.f, 0.f, 0.f}, {0.f, 0.f, 0.f, 0.f},
                   {0.f, 0.f, 0.f, 0.f}, {0.f, 0.f, 0.f, 0.f}};
  unsigned int* Pw = Pp + w * 16 * PSTR;

  float4 vf0, vf1, vf2, vf3;
  {
    const float4* src = reinterpret_cast<const float4*>(Kg + qkvbase + (size_t)trow * D + tcol);
    kf0 = src[0]; kf1 = src[1]; kf2 = src[2]; kf3 = src[3];
    const float4* vs = reinterpret_cast<const float4*>(Vg + qkvbase + (size_t)trow * D + tcol);
    vf0 = vs[0]; vf1 = vs[1]; vf2 = vs[2]; vf3 = vs[3];
  }
  mw = mrow[0];
  for (int t = 0; t < 32; ++t) {
    __syncthreads();
    *reinterpret_cast<short8*>(&Kt[trow * LDK + tcol]) = cvt8(kf0, kf1);
    *reinterpret_cast<short8*>(&Kt[trow * LDK + tcol + 8]) = cvt8(kf2, kf3);
    {  // V transpose, XOR-granule swizzle (<=2-way banks)
      float yy[16] = {vf0.x, vf0.y, vf0.z, vf0.w, vf1.x, vf1.y, vf1.z, vf1.w,
                      vf2.x, vf2.y, vf2.z, vf2.w, vf3.x, vf3.y, vf3.z, vf3.w};
#pragma unroll
      for (int j = 0; j < 16; ++j) {
        int d = tcol + j;
        int pg = (trow >> 3) ^ ((d >> 3) & 7);
        Vt[d * LDK + pg * 8 + (trow & 7)] = (unsigned short)f2bfu(yy[j]);
      }
    }
    __syncthreads();
    if (t < 31) {
      const float4* src = reinterpret_cast<const float4*>(
          Kg + qkvbase + (size_t)((t + 1) * 64 + trow) * D + tcol);
      kf0 = src[0]; kf1 = src[1]; kf2 = src[2]; kf3 = src[3];
      const float4* vs = reinterpret_cast<const float4*>(
          Vg + qkvbase + (size_t)((t + 1) * 64 + trow) * D + tcol);
      vf0 = vs[0]; vf1 = vs[1]; vf2 = vs[2]; vf3 = vs[3];
    }
    unsigned long long mwn = (t < 31) ? mrow[t + 1] : 0ULL;
    const int k0 = t * 64;
#pragma unroll
    for (int kt = 0; kt < 4; ++kt) {
      short8 bk0 = *reinterpret_cast<const short8*>(&Kt[(kt * 16 + ln15) * LDK + (quad << 3)]);
      short8 bk1 = *reinterpret_cast<const short8*>(&Kt[(kt * 16 + ln15) * LDK + 32 + (quad << 3)]);
      f32x4 acc = {0.f, 0.f, 0.f, 0.f};
      acc = __builtin_amdgcn_mfma_f32_16x16x32_bf16(bk0, aq0, acc, 0, 0, 0);
      acc = __builtin_amdgcn_mfma_f32_16x16x32_bf16(bk1, aq1, acc, 0, 0, 0);
      unsigned int nib = (unsigned int)(mw >> (kt * 16 + quad * 4)) & 0xFu;
      f32x4 p;
#pragma unroll
      for (int r = 0; r < 4; ++r) {
        float e = __expf(acc[r] * 0.125f) * rinv;
        p[r] = ((nib >> r) & 1u) ? e : 0.f;
      }
      *reinterpret_cast<f32x4*>(arow + k0 + kt * 16 + quad * 4) = p;  // 16B store
      Pw[ln15 * PSTR + kt * 8 + quad * 2] = packbf2(p[0], p[1]);
      Pw[ln15 * PSTR + kt * 8 + quad * 2 + 1] = packbf2(p[2], p[3]);
    }
    // PV: A-frag from wave-private P region (no barrier needed)
#pragma unroll
    for (int kc = 0; kc < 2; ++kc) {
      short8 ap = *reinterpret_cast<const short8*>(&Pw[ln15 * PSTR + kc * 16 + quad * 4]);
#pragma unroll
      for (int c = 0; c < 4; ++c) {
        int dr = c * 16 + ln15;
        int pg = (4 * kc + quad) ^ ((dr >> 3) & 7);
        short8 bv = *reinterpret_cast<const short8*>(&Vt[dr * LDK + pg * 8]);
        oacc[c] = __builtin_amdgcn_mfma_f32_16x16x32_bf16(ap, bv, oacc[c], 0, 0, 0);
      }
    }
    mw = mwn;
  }

  // epilogue: O store (C rows = query offset quad*4+r, cols = d = c*16+ln15)
#pragma unroll
  for (int c = 0; c < 4; ++c) {
#pragma unroll
    for (int r = 0; r < 4; ++r) {
      Og[qkvbase + (size_t)(q0 + w * 16 + quad * 4 + r) * D + c * 16 + ln15] = oacc[c][r];
    }
  }
}

extern "C" void kernel_launch(void* const* d_in, const int* in_sizes, int n_in,
                              void* d_out, int out_size, void* d_ws, size_t ws_size,
                              hipStream_t stream) {
  const float* q = (const float*)d_in[0];
  const float* k = (const float*)d_in[1];
  const float* v = (const float*)d_in[2];
  const int* m = (const int*)d_in[3];
  float* outp = (float*)d_out;
  float* attnp = outp + (size_t)BB * HH * S * D;
  unsigned long long* bits = (unsigned long long*)d_ws;  // 1 MB

  const int nwords = BB * S * (S / 64);  // 131072
  pack_mask_kernel<<<nwords / 4, 256, 0, stream>>>(m, bits);
  dim3 grid(BB * HH, S / 64);
  attn_kernel<<<grid, 256, 0, stream>>>(q, k, v, bits, outp, attnp);
}